// Round 1
// baseline (476.373 us; speedup 1.0000x reference)
//
#include <hip/hip_runtime.h>
#include <math.h>

#define NB      16
#define DIM     2048
#define NKVh    8
#define HDIM    64
#define GRP     4
#define MAXSEQ  4096
#define TPOS    4095
#define FFH     5632
#define NSPLIT  8
#define CHUNK   512

// workspace offsets (floats)
#define XN_OFF   0          // 16*2048
#define Q_OFF    32768      // 16*2048 (pre-scaled, roped q)
#define ATTN_OFF 65536      // 16*2048
#define H_OFF    98304      // 16*2048
#define HN_OFF   131072     // 16*2048
#define H1_OFF   163840     // 16*5632
#define H3_OFF   253952     // 16*2048
#define PML_OFF  286720     // 16*8*4*8 * 2
#define PO_OFF   294912     // 16*8*4*8 * 64

// ---------------------------------------------------------------- RMSNorm
__global__ __launch_bounds__(256) void rmsnorm_k(const float* __restrict__ x,
    const float* __restrict__ w, float* __restrict__ o) {
  int b = blockIdx.x;
  const float* xr = x + b * DIM;
  float ss = 0.f;
#pragma unroll
  for (int i = 0; i < DIM / 256; ++i) {
    float v = xr[threadIdx.x + i * 256];
    ss += v * v;
  }
#pragma unroll
  for (int m = 32; m >= 1; m >>= 1) ss += __shfl_xor(ss, m, 64);
  __shared__ float sred[4];
  if ((threadIdx.x & 63) == 0) sred[threadIdx.x >> 6] = ss;
  __syncthreads();
  float r = rsqrtf((sred[0] + sred[1] + sred[2] + sred[3]) * (1.f / DIM) + 1e-6f);
#pragma unroll
  for (int i = 0; i < DIM / 256; ++i) {
    int idx = threadIdx.x + i * 256;
    o[b * DIM + idx] = w[idx] * xr[idx] * r;
  }
}

// ---------------------------------------------------------------- GEMV core
// Block = 128 threads (2 waves). Computes rows row0..row0+3 for all 16 batches.
// lane = b4*16 + lk : b4 in 0..3 owns batches {b4, b4+4, b4+8, b4+12},
// lk in 0..15 strides the K dimension (float4 granularity). Wave w takes half of K.
// After: wave 0 lanes hold final acc[r][j] (batch = b4 + 4*j).
template <int K4>
__device__ inline void gemv_core(const float* __restrict__ W,
                                 const float* __restrict__ X,
                                 int row0, float acc[4][4]) {
  const int lane = threadIdx.x & 63;
  const int wv   = threadIdx.x >> 6;
  const int lk   = lane & 15;
  const int b4   = lane >> 4;
  const float4* __restrict__ Wv = (const float4*)W;
  const float4* __restrict__ Xv = (const float4*)X;
#pragma unroll
  for (int r = 0; r < 4; ++r)
#pragma unroll
    for (int j = 0; j < 4; ++j) acc[r][j] = 0.f;

  const int half = K4 / 2;
  int k4 = wv * half + lk;
#pragma unroll 2
  for (int i = 0; i < half / 16; ++i, k4 += 16) {
    float4 xb[4];
#pragma unroll
    for (int j = 0; j < 4; ++j) xb[j] = Xv[(b4 + 4 * j) * K4 + k4];
#pragma unroll
    for (int r = 0; r < 4; ++r) {
      float4 wr = Wv[(row0 + r) * K4 + k4];
#pragma unroll
      for (int j = 0; j < 4; ++j)
        acc[r][j] += wr.x * xb[j].x + wr.y * xb[j].y + wr.z * xb[j].z + wr.w * xb[j].w;
    }
  }
  // reduce across the 16 k-lanes
#pragma unroll
  for (int m = 1; m < 16; m <<= 1)
#pragma unroll
    for (int r = 0; r < 4; ++r)
#pragma unroll
      for (int j = 0; j < 4; ++j) acc[r][j] += __shfl_xor(acc[r][j], m, 64);
  // combine the two waves via LDS
  __shared__ float sred[4][4][4];  // [b4][r][j]
  if (wv == 1 && lk == 0) {
#pragma unroll
    for (int r = 0; r < 4; ++r)
#pragma unroll
      for (int j = 0; j < 4; ++j) sred[b4][r][j] = acc[r][j];
  }
  __syncthreads();
  if (wv == 0) {
#pragma unroll
    for (int r = 0; r < 4; ++r)
#pragma unroll
      for (int j = 0; j < 4; ++j) acc[r][j] += sred[b4][r][j];
  }
}

// ---------------------------------------------------------------- QKV + RoPE
__global__ __launch_bounds__(128) void qkv_k(const float* __restrict__ xn,
    const float* __restrict__ wq, const float* __restrict__ wk,
    const float* __restrict__ wv, const float* __restrict__ fc,
    const float* __restrict__ fs, float* __restrict__ qo,
    float* __restrict__ ck, float* __restrict__ cv) {
  int row0 = blockIdx.x * 4;  // 0..3068 over [q 2048 | k 512 | v 512]
  const float* W;
  int lr, kind;
  if (row0 < DIM)            { W = wq; lr = row0;             kind = 0; }
  else if (row0 < DIM + 512) { W = wk; lr = row0 - DIM;       kind = 1; }
  else                       { W = wv; lr = row0 - DIM - 512; kind = 2; }
  float acc[4][4];
  gemv_core<512>(W, xn, lr, acc);
  if ((threadIdx.x >> 6) != 0 || (threadIdx.x & 15) != 0) return;
  int b4 = (threadIdx.x >> 4) & 3;
  int dl = lr & 63;      // head-local dim of row lr (multiple of 4)
  int j0 = dl >> 1;
  float c0 = fc[j0], s0 = fs[j0], c1 = fc[j0 + 1], s1 = fs[j0 + 1];
  const float QS = 0.125f * 1.44269504088896f;  // 1/sqrt(64) * log2(e)
#pragma unroll
  for (int j = 0; j < 4; ++j) {
    int b = b4 + 4 * j;
    float a0 = acc[0][j], a1 = acc[1][j], a2 = acc[2][j], a3 = acc[3][j];
    float o0 = a0 * c0 - a1 * s0, o1 = a0 * s0 + a1 * c0;
    float o2 = a2 * c1 - a3 * s1, o3 = a2 * s1 + a3 * c1;
    if (kind == 0) {
      float* qp = qo + b * DIM + lr;
      qp[0] = o0 * QS; qp[1] = o1 * QS; qp[2] = o2 * QS; qp[3] = o3 * QS;
    } else {
      int kvh = lr >> 6;
      float* cp = (kind == 1 ? ck : cv) +
                  (((size_t)b * MAXSEQ + TPOS) * NKVh + kvh) * HDIM + dl;
      cp[0] = o0; cp[1] = o1; cp[2] = o2; cp[3] = o3;
    }
  }
}

// ---------------------------------------------------------------- attention (split-T)
__global__ __launch_bounds__(256) void attn_part_k(const float* __restrict__ q,
    const float* __restrict__ ck, const float* __restrict__ cv,
    float* __restrict__ pml, float* __restrict__ po) {
  int blk = blockIdx.x;
  int sp = blk & (NSPLIT - 1);
  int bk = blk / NSPLIT;  // b*8+kv
  int kv = bk & 7, b = bk >> 3;
  int w = threadIdx.x >> 6, lane = threadIdx.x & 63;
  int tg = lane >> 4, lk = lane & 15;

  float4 q4[GRP];
#pragma unroll
  for (int g = 0; g < GRP; ++g)
    q4[g] = *(const float4*)&q[b * DIM + (kv * GRP + g) * HDIM + lk * 4];

  float m[GRP], l[GRP];
  float4 o[GRP];
#pragma unroll
  for (int g = 0; g < GRP; ++g) {
    m[g] = -1e30f; l[g] = 0.f;
    o[g].x = 0.f; o[g].y = 0.f; o[g].z = 0.f; o[g].w = 0.f;
  }
  const float4* Kb = (const float4*)ck + (size_t)b * (MAXSEQ * NKVh * HDIM / 4) + kv * (HDIM / 4);
  const float4* Vb = (const float4*)cv + (size_t)b * (MAXSEQ * NKVh * HDIM / 4) + kv * (HDIM / 4);
  int t0 = sp * CHUNK + w * 4 + tg;
#pragma unroll 2
  for (int it = 0; it < CHUNK / 16; ++it) {
    int t = t0 + it * 16;
    float4 kr = Kb[(size_t)t * (NKVh * HDIM / 4) + lk];
    float s[GRP];
#pragma unroll
    for (int g = 0; g < GRP; ++g)
      s[g] = kr.x * q4[g].x + kr.y * q4[g].y + kr.z * q4[g].z + kr.w * q4[g].w;
#pragma unroll
    for (int msk = 1; msk < 16; msk <<= 1)
#pragma unroll
      for (int g = 0; g < GRP; ++g) s[g] += __shfl_xor(s[g], msk, 64);
    float4 vr = Vb[(size_t)t * (NKVh * HDIM / 4) + lk];
#pragma unroll
    for (int g = 0; g < GRP; ++g) {
      float mn = fmaxf(m[g], s[g]);
      float sc = exp2f(m[g] - mn);
      float p  = exp2f(s[g] - mn);
      l[g] = l[g] * sc + p;
      o[g].x = o[g].x * sc + p * vr.x;
      o[g].y = o[g].y * sc + p * vr.y;
      o[g].z = o[g].z * sc + p * vr.z;
      o[g].w = o[g].w * sc + p * vr.w;
      m[g] = mn;
    }
  }
  __shared__ float sml[16][GRP][2];
  __shared__ float so[16][GRP][HDIM];
  int set = w * 4 + tg;
#pragma unroll
  for (int g = 0; g < GRP; ++g) {
    *(float4*)&so[set][g][lk * 4] = o[g];
    if (lk == 0) { sml[set][g][0] = m[g]; sml[set][g][1] = l[g]; }
  }
  __syncthreads();
  // combine 16 partial sets; one thread per (g, d)
  int g = threadIdx.x >> 6, d = threadIdx.x & 63;
  float M = -1e30f;
#pragma unroll
  for (int s2 = 0; s2 < 16; ++s2) M = fmaxf(M, sml[s2][g][0]);
  float L = 0.f, O = 0.f;
#pragma unroll
  for (int s2 = 0; s2 < 16; ++s2) {
    float e = exp2f(sml[s2][g][0] - M);
    L += e * sml[s2][g][1];
    O += e * so[s2][g][d];
  }
  int idx = (bk * GRP + g) * NSPLIT + sp;
  po[idx * HDIM + d] = O;
  if (d == 0) { pml[idx * 2] = M; pml[idx * 2 + 1] = L; }
}

__global__ __launch_bounds__(256) void attn_comb_k(const float* __restrict__ pml,
    const float* __restrict__ po, float* __restrict__ attn) {
  int t = blockIdx.x * 256 + threadIdx.x;  // 0..32767
  int d = t & 63, bkg = t >> 6;            // bkg = (b*8+kv)*4+g
  float M = -1e30f;
#pragma unroll
  for (int sp = 0; sp < NSPLIT; ++sp) M = fmaxf(M, pml[(bkg * NSPLIT + sp) * 2]);
  float L = 0.f, O = 0.f;
#pragma unroll
  for (int sp = 0; sp < NSPLIT; ++sp) {
    float e = exp2f(pml[(bkg * NSPLIT + sp) * 2] - M);
    L += e * pml[(bkg * NSPLIT + sp) * 2 + 1];
    O += e * po[(bkg * NSPLIT + sp) * HDIM + d];
  }
  attn[bkg * HDIM + d] = O / L;  // == b*2048 + (kv*4+g)*64 + d
}

// ---------------------------------------------------------------- wo + residual
__global__ __launch_bounds__(128) void wo_k(const float* __restrict__ attn,
    const float* __restrict__ wo, const float* __restrict__ x,
    float* __restrict__ h) {
  int row0 = blockIdx.x * 4;
  float acc[4][4];
  gemv_core<512>(wo, attn, row0, acc);
  if ((threadIdx.x >> 6) != 0 || (threadIdx.x & 15) != 0) return;
  int b4 = (threadIdx.x >> 4) & 3;
#pragma unroll
  for (int j = 0; j < 4; ++j) {
    int b = b4 + 4 * j;
#pragma unroll
    for (int r = 0; r < 4; ++r)
      h[b * DIM + row0 + r] = x[b * DIM + row0 + r] + acc[r][j];
  }
}

// ---------------------------------------------------------------- w1(silu) & w3
__global__ __launch_bounds__(128) void ffn13_k(const float* __restrict__ hn,
    const float* __restrict__ w1, const float* __restrict__ w3,
    float* __restrict__ h1, float* __restrict__ h3) {
  int row0 = blockIdx.x * 4;
  bool is1 = row0 < FFH;
  const float* W = is1 ? w1 : w3;
  int lr = is1 ? row0 : row0 - FFH;
  float acc[4][4];
  gemv_core<512>(W, hn, lr, acc);
  if ((threadIdx.x >> 6) != 0 || (threadIdx.x & 15) != 0) return;
  int b4 = (threadIdx.x >> 4) & 3;
#pragma unroll
  for (int j = 0; j < 4; ++j) {
    int b = b4 + 4 * j;
#pragma unroll
    for (int r = 0; r < 4; ++r) {
      float v = acc[r][j];
      if (is1) h1[b * FFH + lr + r] = v / (1.f + expf(-v));
      else     h3[b * DIM + lr + r] = v;
    }
  }
}

// ---------------------------------------------------------------- w2 + residuals
__global__ __launch_bounds__(128) void ffn2_k(const float* __restrict__ h1,
    const float* __restrict__ w2, const float* __restrict__ h,
    const float* __restrict__ h3, float* __restrict__ out) {
  int row0 = blockIdx.x * 4;
  float acc[4][4];
  gemv_core<1408>(w2, h1, row0, acc);
  if ((threadIdx.x >> 6) != 0 || (threadIdx.x & 15) != 0) return;
  int b4 = (threadIdx.x >> 4) & 3;
#pragma unroll
  for (int j = 0; j < 4; ++j) {
    int b = b4 + 4 * j;
#pragma unroll
    for (int r = 0; r < 4; ++r)
      out[b * DIM + row0 + r] = h[b * DIM + row0 + r] + h3[b * DIM + row0 + r] + acc[r][j];
  }
}

// ---------------------------------------------------------------- launch
extern "C" void kernel_launch(void* const* d_in, const int* in_sizes, int n_in,
                              void* d_out, int out_size, void* d_ws, size_t ws_size,
                              hipStream_t stream) {
  (void)in_sizes; (void)n_in; (void)out_size; (void)ws_size;
  const float* x   = (const float*)d_in[0];
  const float* fc  = (const float*)d_in[1];
  const float* fs  = (const float*)d_in[2];
  float*       ck  = (float*)d_in[3];
  float*       cv  = (float*)d_in[4];
  const float* wq  = (const float*)d_in[5];
  const float* wk  = (const float*)d_in[6];
  const float* wvp = (const float*)d_in[7];
  const float* wo  = (const float*)d_in[8];
  const float* w1  = (const float*)d_in[9];
  const float* w2  = (const float*)d_in[10];
  const float* w3  = (const float*)d_in[11];
  const float* anw = (const float*)d_in[12];
  const float* fnw = (const float*)d_in[13];
  float* ws  = (float*)d_ws;
  float* out = (float*)d_out;

  rmsnorm_k<<<NB, 256, 0, stream>>>(x, anw, ws + XN_OFF);
  qkv_k<<<(DIM + 512 + 512) / 4, 128, 0, stream>>>(ws + XN_OFF, wq, wk, wvp, fc, fs,
                                                   ws + Q_OFF, ck, cv);
  attn_part_k<<<NB * NKVh * NSPLIT, 256, 0, stream>>>(ws + Q_OFF, ck, cv,
                                                      ws + PML_OFF, ws + PO_OFF);
  attn_comb_k<<<(NB * DIM) / 256, 256, 0, stream>>>(ws + PML_OFF, ws + PO_OFF, ws + ATTN_OFF);
  wo_k<<<DIM / 4, 128, 0, stream>>>(ws + ATTN_OFF, wo, x, ws + H_OFF);
  rmsnorm_k<<<NB, 256, 0, stream>>>(ws + H_OFF, fnw, ws + HN_OFF);
  ffn13_k<<<(FFH + DIM) / 4, 128, 0, stream>>>(ws + HN_OFF, w1, w3, ws + H1_OFF, ws + H3_OFF);
  ffn2_k<<<DIM / 4, 128, 0, stream>>>(ws + H1_OFF, w2, ws + H_OFF, ws + H3_OFF, out);
}